// Round 13
// baseline (5257.557 us; speedup 1.0000x reference)
//
#include <hip/hip_runtime.h>
#include <hip/hip_fp16.h>
#include <math.h>

#define T_ 8
#define N_ 20000
#define E_ 320000
#define ETOT_ (E_ + N_)
#define FIN_ 32
#define C1_ 256   // HEADS*HID
#define HID_ 64
#define G3_ 384   // 3*GH
#define GH_ 128
#define MB_ 32    // edges per block (R13: halved -> 32 AGPR acc, 24 waves/CU target)
#define MT_ 2     // M-tiles per wave = MB_/16
#define LDP_ 136  // padded inner dim for LDS state arrays
#define NPACK_ (24 * 4 * 64 * 8)   // packed weight elems per matrix

typedef __attribute__((ext_vector_type(8))) _Float16 h8v;
typedef __attribute__((ext_vector_type(4))) float f4v;

// ---------------- helpers ----------------
__device__ __forceinline__ float wave_sum(float v) {
#pragma unroll
  for (int off = 32; off; off >>= 1) v += __shfl_down(v, off);
  return v;
}
__device__ __forceinline__ float sigmoidf_(float x) { return 1.f / (1.f + __expf(-x)); }
__device__ __forceinline__ float tanhf_(float x) {
  float e2 = __expf(2.f * x);
  return 1.f - 2.f / (e2 + 1.f);
}
__device__ __forceinline__ unsigned short f2h(float f) {
  return __half_as_ushort(__float2half_rn(f));
}
__device__ __forceinline__ float h2f(unsigned short u) {
  return __half2float(__ushort_as_half(u));
}
__device__ __forceinline__ void edge_sd(const int* ei, int e, int& s, int& d) {
  if (e < E_) { s = ei[e]; d = ei[E_ + e]; }
  else { s = e - E_; d = e - E_; }
}

// ---------------- CSR build (by dst) ----------------
__global__ void k_hist(const int* __restrict__ ei, int* __restrict__ counts) {
  int e = blockIdx.x * 256 + threadIdx.x;
  if (e >= ETOT_) return;
  int s, d; edge_sd(ei, e, s, d);
  atomicAdd(&counts[d], 1);
}

__global__ void k_scan(const int* __restrict__ counts, int* __restrict__ indptr) {
  __shared__ int tmp[1024];
  __shared__ int carry;
  int tid = threadIdx.x;
  if (tid == 0) { carry = 0; indptr[0] = 0; }
  __syncthreads();
  for (int base = 0; base < N_; base += 1024) {
    int i = base + tid;
    int v = (i < N_) ? counts[i] : 0;
    tmp[tid] = v;
    __syncthreads();
    for (int off = 1; off < 1024; off <<= 1) {
      int add = (tid >= off) ? tmp[tid - off] : 0;
      __syncthreads();
      tmp[tid] += add;
      __syncthreads();
    }
    if (i < N_) indptr[i + 1] = carry + tmp[tid];
    __syncthreads();
    if (tid == 1023) carry += tmp[1023];
    __syncthreads();
  }
}

__global__ void k_copy(const int* __restrict__ indptr, int* __restrict__ cursors) {
  int i = blockIdx.x * 256 + threadIdx.x;
  if (i < N_) cursors[i] = indptr[i];
}

__global__ void k_scatter(const int* __restrict__ ei, int* __restrict__ cursors,
                          int* __restrict__ csr_src) {
  int e = blockIdx.x * 256 + threadIdx.x;
  if (e >= ETOT_) return;
  int s, d; edge_sd(ei, e, s, d);
  int pos = atomicAdd(&cursors[d], 1);
  csr_src[pos] = s;
}

// ---------------- weight pack: W[384][128] fp32 -> B-fragment-ordered fp16 ----
__global__ void k_packW16(const float* __restrict__ W, unsigned short* __restrict__ Bh) {
  int idx = blockIdx.x * 256 + threadIdx.x;
  if (idx >= NPACK_) return;
  int j = idx & 7, lane = (idx >> 3) & 63, ks = (idx >> 9) & 3, nt = idx >> 11;
  int n = nt * 16 + (lane & 15);
  int k = ks * 32 + (lane >> 4) * 8 + j;
  Bh[idx] = f2h(W[n * GH_ + k]);
}

// ---------------- GAT kernels (T-batched via blockIdx.y; strides in elems) ----
__global__ __launch_bounds__(256) void k_gat1_lin(
    const float* __restrict__ x, size_t xs, const float* __restrict__ W1,
    const float* __restrict__ as1, const float* __restrict__ ad1,
    unsigned short* __restrict__ hlin, size_t hs,
    float* __restrict__ als, float* __restrict__ ald, size_t avs) {
  size_t t = blockIdx.y;
  x += t * xs; hlin += t * hs; als += t * avs; ald += t * avs;
  int n = blockIdx.x;
  int j = threadIdx.x;
  __shared__ float sx[FIN_];
  if (j < FIN_) sx[j] = x[n * FIN_ + j];
  __syncthreads();
  float acc = 0.f;
#pragma unroll
  for (int k = 0; k < FIN_; ++k) acc = fmaf(sx[k], W1[k * C1_ + j], acc);
  hlin[(size_t)n * C1_ + j] = f2h(acc);
  int h = j >> 6, c = j & 63;
  float vs = wave_sum(acc * as1[h * 64 + c]);
  float vd = wave_sum(acc * ad1[h * 64 + c]);
  if (c == 0) { als[n * 4 + h] = vs; ald[n * 4 + h] = vd; }
}

// ex arrays eliminated (R12): attn stores only per-node max + exp-sum; agg
// recomputes the weight from the L2-hot als table. Bit-identical expf input.
__global__ __launch_bounds__(256) void k_gat1_attn(
    const int* __restrict__ csr_src, const int* __restrict__ indptr,
    const float* __restrict__ als, const float* __restrict__ ald, size_t avs,
    float* __restrict__ sums, float* __restrict__ mxs, size_t ss) {
  size_t t = blockIdx.y;
  als += t * avs; ald += t * avs; sums += t * ss; mxs += t * ss;
  int w = threadIdx.x >> 6, lane = threadIdx.x & 63;
  int n = blockIdx.x * 4 + w;
  int s0 = indptr[n], s1 = indptr[n + 1];
  float adv[4], mx[4], sm[4];
#pragma unroll
  for (int h = 0; h < 4; ++h) { adv[h] = ald[n * 4 + h]; mx[h] = -1e30f; sm[h] = 0.f; }
  for (int e = s0 + lane; e < s1; e += 64) {
    int s = csr_src[e];
#pragma unroll
    for (int h = 0; h < 4; ++h) {
      float sc = als[s * 4 + h] + adv[h];
      sc = sc >= 0.f ? sc : 0.2f * sc;
      mx[h] = fmaxf(mx[h], sc);
    }
  }
#pragma unroll
  for (int h = 0; h < 4; ++h) {
#pragma unroll
    for (int off = 32; off; off >>= 1) mx[h] = fmaxf(mx[h], __shfl_xor(mx[h], off));
  }
  for (int e = s0 + lane; e < s1; e += 64) {
    int s = csr_src[e];
#pragma unroll
    for (int h = 0; h < 4; ++h) {
      float sc = als[s * 4 + h] + adv[h];
      sc = sc >= 0.f ? sc : 0.2f * sc;
      sm[h] += __expf(sc - mx[h]);
    }
  }
#pragma unroll
  for (int h = 0; h < 4; ++h) sm[h] = wave_sum(sm[h]);
  if (lane == 0) {
#pragma unroll
    for (int h = 0; h < 4; ++h) { sums[n * 4 + h] = sm[h]; mxs[n * 4 + h] = mx[h]; }
  }
}

// Fused: gat1 aggregation (ELU) -> h1 in LDS -> gat2 linear + attn logits.
__global__ __launch_bounds__(256) void k_agg1lin2(
    const int* __restrict__ csr_src, const int* __restrict__ indptr,
    const float* __restrict__ als, const float* __restrict__ ald,
    const float* __restrict__ sums, const float* __restrict__ mxs, size_t ss,
    const unsigned short* __restrict__ hlin, size_t hs, const float* __restrict__ b1,
    const float* __restrict__ W2, const float* __restrict__ as2, const float* __restrict__ ad2,
    unsigned short* __restrict__ hlin2, size_t h2s,
    float* __restrict__ als2, float* __restrict__ ald2, size_t a2s) {
  size_t t = blockIdx.y;
  als += t * ss; ald += t * ss; sums += t * ss; mxs += t * ss; hlin += t * hs;
  hlin2 += t * h2s; als2 += t * a2s; ald2 += t * a2s;
  int n = blockIdx.x;
  int j = threadIdx.x;
  int w = j >> 6, lane = j & 63;
  __shared__ float sh1[C1_];
  __shared__ float part[4][68];
  int s0 = indptr[n], s1 = indptr[n + 1];
  float inv = 1.f / (sums[n * 4 + w] + 1e-16f);
  float mxw = mxs[n * 4 + w];
  float adv = ald[n * 4 + w];
  float acc = 0.f;
  int e = s0;
  for (; e + 4 <= s1; e += 4) {
    int i0 = csr_src[e], i1 = csr_src[e + 1], i2 = csr_src[e + 2], i3 = csr_src[e + 3];
    float s0v = als[i0 * 4 + w] + adv;
    float s1v = als[i1 * 4 + w] + adv;
    float s2v = als[i2 * 4 + w] + adv;
    float s3v = als[i3 * 4 + w] + adv;
    s0v = s0v >= 0.f ? s0v : 0.2f * s0v;
    s1v = s1v >= 0.f ? s1v : 0.2f * s1v;
    s2v = s2v >= 0.f ? s2v : 0.2f * s2v;
    s3v = s3v >= 0.f ? s3v : 0.2f * s3v;
    float a0 = __expf(s0v - mxw) * inv;
    float a1 = __expf(s1v - mxw) * inv;
    float a2 = __expf(s2v - mxw) * inv;
    float a3 = __expf(s3v - mxw) * inv;
    float g0 = h2f(hlin[(size_t)i0 * C1_ + j]);
    float g1 = h2f(hlin[(size_t)i1 * C1_ + j]);
    float g2 = h2f(hlin[(size_t)i2 * C1_ + j]);
    float g3 = h2f(hlin[(size_t)i3 * C1_ + j]);
    acc = fmaf(a0, g0, acc);
    acc = fmaf(a1, g1, acc);
    acc = fmaf(a2, g2, acc);
    acc = fmaf(a3, g3, acc);
  }
  for (; e < s1; ++e) {
    int s = csr_src[e];
    float sc = als[s * 4 + w] + adv;
    sc = sc >= 0.f ? sc : 0.2f * sc;
    acc = fmaf(__expf(sc - mxw) * inv, h2f(hlin[(size_t)s * C1_ + j]), acc);
  }
  float o = acc + b1[j];
  sh1[j] = o > 0.f ? o : expm1f(o);
  __syncthreads();
  float pw = 0.f;
#pragma unroll 4
  for (int kk = 0; kk < 64; ++kk) {
    int k = w * 64 + kk;
    pw = fmaf(sh1[k], W2[k * HID_ + lane], pw);
  }
  part[w][lane] = pw;
  __syncthreads();
  if (w == 0) {
    float a2 = part[0][lane] + part[1][lane] + part[2][lane] + part[3][lane];
    hlin2[(size_t)n * HID_ + lane] = f2h(a2);
    float vs = wave_sum(a2 * as2[lane]);
    float vd = wave_sum(a2 * ad2[lane]);
    if (lane == 0) { als2[n] = vs; ald2[n] = vd; }
  }
}

__global__ __launch_bounds__(256) void k_gat2_attn(
    const int* __restrict__ csr_src, const int* __restrict__ indptr,
    const float* __restrict__ als, const float* __restrict__ ald, size_t a2s,
    float* __restrict__ sums, float* __restrict__ mxs, size_t s2s) {
  size_t t = blockIdx.y;
  als += t * a2s; ald += t * a2s; sums += t * s2s; mxs += t * s2s;
  int w = threadIdx.x >> 6, lane = threadIdx.x & 63;
  int n = blockIdx.x * 4 + w;
  int s0 = indptr[n], s1 = indptr[n + 1];
  float adv = ald[n];
  float mx = -1e30f, sm = 0.f;
  for (int e = s0 + lane; e < s1; e += 64) {
    float sc = als[csr_src[e]] + adv;
    sc = sc >= 0.f ? sc : 0.2f * sc;
    mx = fmaxf(mx, sc);
  }
#pragma unroll
  for (int off = 32; off; off >>= 1) mx = fmaxf(mx, __shfl_xor(mx, off));
  for (int e = s0 + lane; e < s1; e += 64) {
    float sc = als[csr_src[e]] + adv;
    sc = sc >= 0.f ? sc : 0.2f * sc;
    sm += __expf(sc - mx);
  }
  sm = wave_sum(sm);
  if (lane == 0) { sums[n] = sm; mxs[n] = mx; }
}

// writes h2 as fp16 (A-operand of the layer-0 input MFMA); recomputed weights
__global__ __launch_bounds__(256) void k_gat2_agg(
    const int* __restrict__ csr_src, const int* __restrict__ indptr,
    const float* __restrict__ als, const float* __restrict__ ald,
    const float* __restrict__ sums, const float* __restrict__ mxs, size_t s2s,
    const unsigned short* __restrict__ hlin2, size_t h2s, const float* __restrict__ b2,
    unsigned short* __restrict__ h2f16, size_t hos) {
  size_t t = blockIdx.y;
  als += t * s2s; ald += t * s2s; sums += t * s2s; mxs += t * s2s;
  hlin2 += t * h2s; h2f16 += t * hos;
  int w = threadIdx.x >> 6, lane = threadIdx.x & 63;
  int n = blockIdx.x * 4 + w;
  int s0 = indptr[n], s1 = indptr[n + 1];
  float inv = 1.f / (sums[n] + 1e-16f);
  float mxv = mxs[n];
  float adv = ald[n];
  float acc = 0.f;
  int e = s0;
  for (; e + 4 <= s1; e += 4) {
    int i0 = csr_src[e], i1 = csr_src[e + 1], i2 = csr_src[e + 2], i3 = csr_src[e + 3];
    float s0v = als[i0] + adv;
    float s1v = als[i1] + adv;
    float s2v = als[i2] + adv;
    float s3v = als[i3] + adv;
    s0v = s0v >= 0.f ? s0v : 0.2f * s0v;
    s1v = s1v >= 0.f ? s1v : 0.2f * s1v;
    s2v = s2v >= 0.f ? s2v : 0.2f * s2v;
    s3v = s3v >= 0.f ? s3v : 0.2f * s3v;
    float a0 = __expf(s0v - mxv) * inv;
    float a1 = __expf(s1v - mxv) * inv;
    float a2 = __expf(s2v - mxv) * inv;
    float a3 = __expf(s3v - mxv) * inv;
    float g0 = h2f(hlin2[(size_t)i0 * HID_ + lane]);
    float g1 = h2f(hlin2[(size_t)i1 * HID_ + lane]);
    float g2 = h2f(hlin2[(size_t)i2 * HID_ + lane]);
    float g3 = h2f(hlin2[(size_t)i3 * HID_ + lane]);
    acc = fmaf(a0, g0, acc);
    acc = fmaf(a1, g1, acc);
    acc = fmaf(a2, g2, acc);
    acc = fmaf(a3, g3, acc);
  }
  for (; e < s1; ++e) {
    int s = csr_src[e];
    float sc = als[s] + adv;
    sc = sc >= 0.f ? sc : 0.2f * sc;
    acc = fmaf(__expf(sc - mxv) * inv, h2f(hlin2[(size_t)s * HID_ + lane]), acc);
  }
  h2f16[(size_t)n * HID_ + lane] = f2h(acc + b2[lane]);
}

// ---------------- MFMA GRU step (R13: MT=2/MB=32, acc 32 AGPR) ----
// R13: halved per-wave accumulator (16 -> 8 f4v = 32 AGPR). With ~50 VGPR the
// wave footprint ~82 regs fits __launch_bounds__(512,6)'s 85-reg budget ->
// 3 blocks/CU = 24 waves/CU (was 16), +50% latency-hiding streams for this
// latency-bound kernel (HBM 14%, VALU 42%, MFMA 5% -- nothing saturated).
// Cost: 2x block count -> 2x B-fragment L2 requests (~55us/dispatch at L2 BW).
__device__ __forceinline__ void mfma1h(f4v& acc, h8v a, h8v b) {
  acc = __builtin_amdgcn_mfma_f32_16x16x32_f16(a, b, acc, 0, 0, 0);
}

__device__ __forceinline__ void mfma_pass(
    const unsigned short* A_,
    const unsigned short* __restrict__ Bh_,
    int w, int lane, f4v Cr[MT_], f4v Cz[MT_], f4v Cn[MT_]) {
  const int mrow = lane & 15, quad = lane >> 4;
#pragma unroll
  for (int ks = 0; ks < 4; ++ks) {
    h8v A[MT_];
    const int aoff = mrow * LDP_ + ks * 32 + quad * 8;
#pragma unroll
    for (int mt = 0; mt < MT_; ++mt) A[mt] = *(const h8v*)(A_ + aoff + mt * (16 * LDP_));
    {
      const int nt = w;
      const h8v bh = *(const h8v*)(Bh_ + ((size_t)(nt * 4 + ks) * 64 + lane) * 8);
#pragma unroll
      for (int mt = 0; mt < MT_; ++mt) mfma1h(Cr[mt], A[mt], bh);
    }
    {
      const int nt = 8 + w;
      const h8v bh = *(const h8v*)(Bh_ + ((size_t)(nt * 4 + ks) * 64 + lane) * 8);
#pragma unroll
      for (int mt = 0; mt < MT_; ++mt) mfma1h(Cz[mt], A[mt], bh);
    }
    {
      const int nt = 16 + w;
      const h8v bh = *(const h8v*)(Bh_ + ((size_t)(nt * 4 + ks) * 64 + lane) * 8);
#pragma unroll
      for (int mt = 0; mt < MT_; ++mt) mfma1h(Cn[mt], A[mt], bh);
    }
  }
}

__device__ __forceinline__ void mfma_pass_x(
    const unsigned short* __restrict__ h2,
    const int esrc[MT_], const int edst[MT_],
    const unsigned short* __restrict__ Bh_,
    int w, int lane, f4v Cr[MT_], f4v Cz[MT_], f4v Cn[MT_]) {
  const int quad = lane >> 4;
#pragma unroll
  for (int ks = 0; ks < 4; ++ks) {
    h8v A[MT_];
    const int choff = (ks & 1) * 32 + quad * 8;
#pragma unroll
    for (int mt = 0; mt < MT_; ++mt) {
      const int node = (ks < 2) ? esrc[mt] : edst[mt];
      A[mt] = *(const h8v*)(h2 + (size_t)node * HID_ + choff);
    }
    {
      const int nt = w;
      const h8v bh = *(const h8v*)(Bh_ + ((size_t)(nt * 4 + ks) * 64 + lane) * 8);
#pragma unroll
      for (int mt = 0; mt < MT_; ++mt) mfma1h(Cr[mt], A[mt], bh);
    }
    {
      const int nt = 8 + w;
      const h8v bh = *(const h8v*)(Bh_ + ((size_t)(nt * 4 + ks) * 64 + lane) * 8);
#pragma unroll
      for (int mt = 0; mt < MT_; ++mt) mfma1h(Cz[mt], A[mt], bh);
    }
    {
      const int nt = 16 + w;
      const h8v bh = *(const h8v*)(Bh_ + ((size_t)(nt * 4 + ks) * 64 + lane) * 8);
#pragma unroll
      for (int mt = 0; mt < MT_; ++mt) mfma1h(Cn[mt], A[mt], bh);
    }
  }
}

__global__ __launch_bounds__(512, 6) void k_gru_step(
    const unsigned short* __restrict__ h2, const int* __restrict__ ei,
    int seg_e0, int first, int last,
    const unsigned short* __restrict__ pWih0, const unsigned short* __restrict__ pWhh0,
    const unsigned short* __restrict__ pWih1, const unsigned short* __restrict__ pWhh1,
    const float* __restrict__ bih0, const float* __restrict__ bhh0,
    const float* __restrict__ bih1, const float* __restrict__ bhh1,
    const float* __restrict__ Wd1, const float* __restrict__ bd1,
    const float* __restrict__ Wd2, const float* __restrict__ bd2,
    unsigned short* __restrict__ h0g, unsigned short* __restrict__ h1g,
    float* __restrict__ out) {
  __shared__ unsigned short h0h[MB_ * LDP_];
  __shared__ unsigned short h1h[MB_ * LDP_];
  const int tid = threadIdx.x;
  const int lane = tid & 63, w = tid >> 6;
  const int col = lane & 15, quad = lane >> 4;
  const int mrow = lane & 15;
  const int le0 = blockIdx.x * MB_;
  const size_t ge0 = (size_t)seg_e0 + le0;

  int esrc[MT_], edst[MT_];
#pragma unroll
  for (int mt = 0; mt < MT_; ++mt) {
    esrc[mt] = ei[ge0 + mt * 16 + mrow];
    edst[mt] = ei[E_ + ge0 + mt * 16 + mrow];
  }
  // stage fp16 states global -> LDS (NT 16B loads; exactly 1 iter/thread)
  if (!first) {
    for (int i = tid; i < MB_ * 16; i += 512) {
      int e = i >> 4, c = (i & 15) * 8;
      *(h8v*)&h0h[e * LDP_ + c] =
          __builtin_nontemporal_load((const h8v*)(h0g + (size_t)(le0 + e) * GH_ + c));
      *(h8v*)&h1h[e * LDP_ + c] =
          __builtin_nontemporal_load((const h8v*)(h1g + (size_t)(le0 + e) * GH_ + c));
    }
  }

  const int cg = w * 16 + col;
  f4v Cr[MT_], Cz[MT_], Cin[MT_], Chn[MT_];

  // ---- layer 0 ----
#pragma unroll
  for (int mt = 0; mt < MT_; ++mt) {
    Cr[mt] = (f4v){0.f, 0.f, 0.f, 0.f};
    Cz[mt] = (f4v){0.f, 0.f, 0.f, 0.f};
    Cin[mt] = (f4v){0.f, 0.f, 0.f, 0.f};
    Chn[mt] = (f4v){0.f, 0.f, 0.f, 0.f};
  }
  mfma_pass_x(h2, esrc, edst, pWih0, w, lane, Cr, Cz, Cin);  // global-only
  __syncthreads();   // staging visible (drain hidden under pass_x)
  if (!first) mfma_pass(h0h, pWhh0, w, lane, Cr, Cz, Chn);
  __syncthreads();   // all reads of old h0h done
  {
    float biR = bih0[cg] + bhh0[cg];
    float biZ = bih0[128 + cg] + bhh0[128 + cg];
    float biNi = bih0[256 + cg], biNh = bhh0[256 + cg];
#pragma unroll
    for (int mt = 0; mt < MT_; ++mt)
#pragma unroll
      for (int reg = 0; reg < 4; ++reg) {
        int e = mt * 16 + quad * 4 + reg;
        float r = sigmoidf_(Cr[mt][reg] + biR);
        float z = sigmoidf_(Cz[mt][reg] + biZ);
        float n = tanhf_(Cin[mt][reg] + biNi + r * (Chn[mt][reg] + biNh));
        float hp = first ? 0.f : h2f(h0h[e * LDP_ + cg]);
        float hv = (1.f - z) * n + z * hp;
        h0h[e * LDP_ + cg] = f2h(hv);
      }
  }
  __syncthreads();   // new h0h visible

  // ---- layer 1 ----
#pragma unroll
  for (int mt = 0; mt < MT_; ++mt) {
    Cr[mt] = (f4v){0.f, 0.f, 0.f, 0.f};
    Cz[mt] = (f4v){0.f, 0.f, 0.f, 0.f};
    Cin[mt] = (f4v){0.f, 0.f, 0.f, 0.f};
    Chn[mt] = (f4v){0.f, 0.f, 0.f, 0.f};
  }
  mfma_pass(h0h, pWih1, w, lane, Cr, Cz, Cin);
  if (!first) mfma_pass(h1h, pWhh1, w, lane, Cr, Cz, Chn);
  __syncthreads();   // old h1h reads done
  {
    float biR = bih1[cg] + bhh1[cg];
    float biZ = bih1[128 + cg] + bhh1[128 + cg];
    float biNi = bih1[256 + cg], biNh = bhh1[256 + cg];
#pragma unroll
    for (int mt = 0; mt < MT_; ++mt)
#pragma unroll
      for (int reg = 0; reg < 4; ++reg) {
        int e = mt * 16 + quad * 4 + reg;
        float r = sigmoidf_(Cr[mt][reg] + biR);
        float z = sigmoidf_(Cz[mt][reg] + biZ);
        float n = tanhf_(Cin[mt][reg] + biNi + r * (Chn[mt][reg] + biNh));
        float hp = first ? 0.f : h2f(h1h[e * LDP_ + cg]);
        float hv = (1.f - z) * n + z * hp;
        if (!last) {
          h1h[e * LDP_ + cg] = f2h(hv);
        } else {
          unsigned short hb = f2h(hv);
          h1h[e * LDP_ + cg] = hb;
          h0h[e * LDP_ + cg] = f2h(hv - h2f(hb));   // lo stash (h0h free)
        }
      }
  }
  __syncthreads();

  if (!last) {
    for (int i = tid; i < MB_ * 16; i += 512) {
      int e = i >> 4, c = (i & 15) * 8;
      __builtin_nontemporal_store(*(const h8v*)&h0h[e * LDP_ + c],
                                  (h8v*)(h0g + (size_t)(le0 + e) * GH_ + c));
      __builtin_nontemporal_store(*(const h8v*)&h1h[e * LDP_ + c],
                                  (h8v*)(h1g + (size_t)(le0 + e) * GH_ + c));
    }
  } else {
    for (int ee = 0; ee < MB_ / 8; ++ee) {
      int e = w * (MB_ / 8) + ee;
      float acc = 0.f;
#pragma unroll
      for (int kc = 0; kc < 16; ++kc) {
        h8v hv8 = *(const h8v*)&h1h[e * LDP_ + kc * 8];
        h8v lv8 = *(const h8v*)&h0h[e * LDP_ + kc * 8];
#pragma unroll
        for (int j = 0; j < 8; ++j) {
          float hvv = (float)hv8[j] + (float)lv8[j];
          acc = fmaf(hvv, Wd1[(kc * 8 + j) * 64 + lane], acc);
        }
      }
      float rv = fmaxf(acc + bd1[lane], 0.f);
      float contrib = wave_sum(rv * Wd2[lane]);
      if (lane == 0) out[ge0 + e] = contrib + bd2[0];
    }
  }
}

// ---------------- launch ----------------
extern "C" void kernel_launch(void* const* d_in, const int* in_sizes, int n_in,
                              void* d_out, int out_size, void* d_ws, size_t ws_size,
                              hipStream_t stream) {
  (void)in_sizes; (void)n_in; (void)out_size;
  const float* x_seq = (const float*)d_in[0];
  const int*   ei    = (const int*)d_in[1];
  const float* W1    = (const float*)d_in[2];
  const float* as1   = (const float*)d_in[3];
  const float* ad1   = (const float*)d_in[4];
  const float* b1    = (const float*)d_in[5];
  const float* W2    = (const float*)d_in[6];
  const float* as2   = (const float*)d_in[7];
  const float* ad2   = (const float*)d_in[8];
  const float* b2    = (const float*)d_in[9];
  const float* Wih0  = (const float*)d_in[10];
  const float* Whh0  = (const float*)d_in[11];
  const float* bih0  = (const float*)d_in[12];
  const float* bhh0  = (const float*)d_in[13];
  const float* Wih1  = (const float*)d_in[14];
  const float* Whh1  = (const float*)d_in[15];
  const float* bih1  = (const float*)d_in[16];
  const float* bhh1  = (const float*)d_in[17];
  const float* Wd1   = (const float*)d_in[18];
  const float* bd1   = (const float*)d_in[19];
  const float* Wd2   = (const float*)d_in[20];
  const float* bd2   = (const float*)d_in[21];
  float* out = (float*)d_out;

  char* p = (char*)d_ws;
  auto alloc = [&](size_t bytes) -> char* {
    char* r = p;
    p += (bytes + 255) & ~(size_t)255;
    return r;
  };
  auto rnd = [](size_t b) { return (b + 255) & ~(size_t)255; };

  // persistent:
  unsigned short* h2_all = (unsigned short*)alloc((size_t)T_ * N_ * HID_ * 2);  // 20.5 MB
  unsigned short* pWih0 = (unsigned short*)alloc(NPACK_ * 2);
  unsigned short* pWhh0 = (unsigned short*)alloc(NPACK_ * 2);
  unsigned short* pWih1 = (unsigned short*)alloc(NPACK_ * 2);
  unsigned short* pWhh1 = (unsigned short*)alloc(NPACK_ * 2);
  int* counts   = (int*)alloc((size_t)N_ * 4);
  int* indptr   = (int*)alloc((size_t)(N_ + 1) * 4);
  int* cursors  = (int*)alloc((size_t)N_ * 4);
  int* csr      = (int*)alloc((size_t)ETOT_ * 4);

  // per-t element strides
  const size_t S_HL1 = (size_t)N_ * C1_;   // hlin1 fp16
  const size_t S_SU1 = (size_t)N_ * 4;     // als1/ald1/sums1/mxs1 fp32
  const size_t S_HL2 = (size_t)N_ * HID_;  // hlin2 fp16
  const size_t S_SC2 = (size_t)N_;         // als2/ald2/sums2/mxs2 fp32

  // Batched mode needs region >= max(GAT T-batched scratch, full-E GRU states).
  size_t gat_batched = rnd(S_HL1 * 2 * T_) + 4 * rnd(S_SU1 * 4 * T_) +
                       rnd(S_HL2 * 2 * T_) + 4 * rnd(S_SC2 * 4 * T_);
  size_t states1 = 2 * rnd((size_t)E_ * GH_ * 2);          // SEG=1 (merged)
  size_t pers_off = (size_t)(p - (char*)d_ws);
  size_t need_b = gat_batched > states1 ? gat_batched : states1;
  const int batched = (ws_size >= pers_off + need_b + (1u << 20)) ? 1 : 0;
  const size_t TB = batched ? T_ : 1;
  const int segs = batched ? 1 : 2;        // merged segments need full-E states
  const int eseg = E_ / segs;

  // REGION: GAT scratch (phase 1) aliased with GRU fp16 states (phase 2).
  char* region = p;
  unsigned short* hlin1 = (unsigned short*)alloc(S_HL1 * 2 * TB);
  float* als1   = (float*)alloc(S_SU1 * 4 * TB);
  float* ald1   = (float*)alloc(S_SU1 * 4 * TB);
  float* sums1  = (float*)alloc(S_SU1 * 4 * TB);
  float* mxs1   = (float*)alloc(S_SU1 * 4 * TB);
  unsigned short* hlin2 = (unsigned short*)alloc(S_HL2 * 2 * TB);
  float* als2   = (float*)alloc(S_SC2 * 4 * TB);
  float* ald2   = (float*)alloc(S_SC2 * 4 * TB);
  float* sums2  = (float*)alloc(S_SC2 * 4 * TB);
  float* mxs2   = (float*)alloc(S_SC2 * 4 * TB);
  // GRU view (same region): fp16 states 2 x (eseg*GH*2) bytes
  unsigned short* h0g = (unsigned short*)(region);
  unsigned short* h1g = (unsigned short*)(region + rnd((size_t)eseg * GH_ * 2));

  (void)hipMemsetAsync(counts, 0, (size_t)N_ * 4, stream);

  k_hist<<<(ETOT_ + 255) / 256, 256, 0, stream>>>(ei, counts);
  k_scan<<<1, 1024, 0, stream>>>(counts, indptr);
  k_copy<<<(N_ + 255) / 256, 256, 0, stream>>>(indptr, cursors);
  k_scatter<<<(ETOT_ + 255) / 256, 256, 0, stream>>>(ei, cursors, csr);
  const int pb = (NPACK_ + 255) / 256;
  k_packW16<<<pb, 256, 0, stream>>>(Wih0, pWih0);
  k_packW16<<<pb, 256, 0, stream>>>(Whh0, pWhh0);
  k_packW16<<<pb, 256, 0, stream>>>(Wih1, pWih1);
  k_packW16<<<pb, 256, 0, stream>>>(Whh1, pWhh1);

  const int TL = batched ? 1 : T_;
  const unsigned gy = batched ? T_ : 1;
  for (int t = 0; t < TL; ++t) {
    const float* xt = batched ? x_seq : x_seq + (size_t)t * N_ * FIN_;
    unsigned short* h2t = batched ? h2_all : h2_all + (size_t)t * N_ * HID_;
    k_gat1_lin<<<dim3(N_, gy), 256, 0, stream>>>(
        xt, (size_t)N_ * FIN_, W1, as1, ad1, hlin1, S_HL1, als1, ald1, S_SU1);
    k_gat1_attn<<<dim3(N_ / 4, gy), 256, 0, stream>>>(
        csr, indptr, als1, ald1, S_SU1, sums1, mxs1, S_SU1);
    k_agg1lin2<<<dim3(N_, gy), 256, 0, stream>>>(
        csr, indptr, als1, ald1, sums1, mxs1, S_SU1, hlin1, S_HL1, b1,
        W2, as2, ad2, hlin2, S_HL2, als2, ald2, S_SC2);
    k_gat2_attn<<<dim3(N_ / 4, gy), 256, 0, stream>>>(
        csr, indptr, als2, ald2, S_SC2, sums2, mxs2, S_SC2);
    k_gat2_agg<<<dim3(N_ / 4, gy), 256, 0, stream>>>(
        csr, indptr, als2, ald2, sums2, mxs2, S_SC2, hlin2, S_HL2, b2, h2t, S_HL2);
  }

  for (int seg = 0; seg < segs; ++seg) {
    for (int t = 0; t < T_; ++t) {
      const unsigned short* h2t = h2_all + (size_t)t * N_ * HID_;
      k_gru_step<<<eseg / MB_, 512, 0, stream>>>(
          h2t, ei, seg * eseg, (t == 0) ? 1 : 0, (t == T_ - 1) ? 1 : 0,
          pWih0, pWhh0, pWih1, pWhh1,
          bih0, bhh0, bih1, bhh1, Wd1, bd1, Wd2, bd2,
          h0g, h1g, out);
    }
  }
}

// Round 14
// 4194.599 us; speedup vs baseline: 1.2534x; 1.2534x over previous
//
#include <hip/hip_runtime.h>
#include <hip/hip_fp16.h>
#include <math.h>

#define T_ 8
#define N_ 20000
#define E_ 320000
#define ETOT_ (E_ + N_)
#define FIN_ 32
#define C1_ 256   // HEADS*HID
#define HID_ 64
#define G3_ 384   // 3*GH
#define GH_ 128
#define MB_ 64    // edges per block (proven optimum: 8 waves, 64 VGPR + 64 AGPR)
#define MT_ 4     // M-tiles per wave = MB_/16
#define LDP_ 136  // padded inner dim for LDS state arrays
#define NPACK_ (24 * 4 * 64 * 8)   // packed weight elems per matrix

typedef __attribute__((ext_vector_type(8))) _Float16 h8v;
typedef __attribute__((ext_vector_type(4))) float f4v;

// ---------------- helpers ----------------
__device__ __forceinline__ float wave_sum(float v) {
#pragma unroll
  for (int off = 32; off; off >>= 1) v += __shfl_down(v, off);
  return v;
}
__device__ __forceinline__ float sigmoidf_(float x) { return 1.f / (1.f + __expf(-x)); }
__device__ __forceinline__ float tanhf_(float x) {
  float e2 = __expf(2.f * x);
  return 1.f - 2.f / (e2 + 1.f);
}
__device__ __forceinline__ unsigned short f2h(float f) {
  return __half_as_ushort(__float2half_rn(f));
}
__device__ __forceinline__ float h2f(unsigned short u) {
  return __half2float(__ushort_as_half(u));
}
__device__ __forceinline__ void edge_sd(const int* ei, int e, int& s, int& d) {
  if (e < E_) { s = ei[e]; d = ei[E_ + e]; }
  else { s = e - E_; d = e - E_; }
}

// ---------------- CSR build (by dst) ----------------
__global__ void k_hist(const int* __restrict__ ei, int* __restrict__ counts) {
  int e = blockIdx.x * 256 + threadIdx.x;
  if (e >= ETOT_) return;
  int s, d; edge_sd(ei, e, s, d);
  atomicAdd(&counts[d], 1);
}

__global__ void k_scan(const int* __restrict__ counts, int* __restrict__ indptr) {
  __shared__ int tmp[1024];
  __shared__ int carry;
  int tid = threadIdx.x;
  if (tid == 0) { carry = 0; indptr[0] = 0; }
  __syncthreads();
  for (int base = 0; base < N_; base += 1024) {
    int i = base + tid;
    int v = (i < N_) ? counts[i] : 0;
    tmp[tid] = v;
    __syncthreads();
    for (int off = 1; off < 1024; off <<= 1) {
      int add = (tid >= off) ? tmp[tid - off] : 0;
      __syncthreads();
      tmp[tid] += add;
      __syncthreads();
    }
    if (i < N_) indptr[i + 1] = carry + tmp[tid];
    __syncthreads();
    if (tid == 1023) carry += tmp[1023];
    __syncthreads();
  }
}

__global__ void k_copy(const int* __restrict__ indptr, int* __restrict__ cursors) {
  int i = blockIdx.x * 256 + threadIdx.x;
  if (i < N_) cursors[i] = indptr[i];
}

__global__ void k_scatter(const int* __restrict__ ei, int* __restrict__ cursors,
                          int* __restrict__ csr_src) {
  int e = blockIdx.x * 256 + threadIdx.x;
  if (e >= ETOT_) return;
  int s, d; edge_sd(ei, e, s, d);
  int pos = atomicAdd(&cursors[d], 1);
  csr_src[pos] = s;
}

// ---------------- weight pack: W[384][128] fp32 -> B-fragment-ordered fp16 ----
__global__ void k_packW16(const float* __restrict__ W, unsigned short* __restrict__ Bh) {
  int idx = blockIdx.x * 256 + threadIdx.x;
  if (idx >= NPACK_) return;
  int j = idx & 7, lane = (idx >> 3) & 63, ks = (idx >> 9) & 3, nt = idx >> 11;
  int n = nt * 16 + (lane & 15);
  int k = ks * 32 + (lane >> 4) * 8 + j;
  Bh[idx] = f2h(W[n * GH_ + k]);
}

// ---------------- GAT kernels (T-batched via blockIdx.y; strides in elems) ----
__global__ __launch_bounds__(256) void k_gat1_lin(
    const float* __restrict__ x, size_t xs, const float* __restrict__ W1,
    const float* __restrict__ as1, const float* __restrict__ ad1,
    unsigned short* __restrict__ hlin, size_t hs,
    float* __restrict__ als, float* __restrict__ ald, size_t avs) {
  size_t t = blockIdx.y;
  x += t * xs; hlin += t * hs; als += t * avs; ald += t * avs;
  int n = blockIdx.x;
  int j = threadIdx.x;
  __shared__ float sx[FIN_];
  if (j < FIN_) sx[j] = x[n * FIN_ + j];
  __syncthreads();
  float acc = 0.f;
#pragma unroll
  for (int k = 0; k < FIN_; ++k) acc = fmaf(sx[k], W1[k * C1_ + j], acc);
  hlin[(size_t)n * C1_ + j] = f2h(acc);
  int h = j >> 6, c = j & 63;
  float vs = wave_sum(acc * as1[h * 64 + c]);
  float vd = wave_sum(acc * ad1[h * 64 + c]);
  if (c == 0) { als[n * 4 + h] = vs; ald[n * 4 + h] = vd; }
}

// ex arrays eliminated (R12): attn stores only per-node max + exp-sum; agg
// recomputes the weight from the L2-hot als table. Bit-identical expf input.
__global__ __launch_bounds__(256) void k_gat1_attn(
    const int* __restrict__ csr_src, const int* __restrict__ indptr,
    const float* __restrict__ als, const float* __restrict__ ald, size_t avs,
    float* __restrict__ sums, float* __restrict__ mxs, size_t ss) {
  size_t t = blockIdx.y;
  als += t * avs; ald += t * avs; sums += t * ss; mxs += t * ss;
  int w = threadIdx.x >> 6, lane = threadIdx.x & 63;
  int n = blockIdx.x * 4 + w;
  int s0 = indptr[n], s1 = indptr[n + 1];
  float adv[4], mx[4], sm[4];
#pragma unroll
  for (int h = 0; h < 4; ++h) { adv[h] = ald[n * 4 + h]; mx[h] = -1e30f; sm[h] = 0.f; }
  for (int e = s0 + lane; e < s1; e += 64) {
    int s = csr_src[e];
#pragma unroll
    for (int h = 0; h < 4; ++h) {
      float sc = als[s * 4 + h] + adv[h];
      sc = sc >= 0.f ? sc : 0.2f * sc;
      mx[h] = fmaxf(mx[h], sc);
    }
  }
#pragma unroll
  for (int h = 0; h < 4; ++h) {
#pragma unroll
    for (int off = 32; off; off >>= 1) mx[h] = fmaxf(mx[h], __shfl_xor(mx[h], off));
  }
  for (int e = s0 + lane; e < s1; e += 64) {
    int s = csr_src[e];
#pragma unroll
    for (int h = 0; h < 4; ++h) {
      float sc = als[s * 4 + h] + adv[h];
      sc = sc >= 0.f ? sc : 0.2f * sc;
      sm[h] += __expf(sc - mx[h]);
    }
  }
#pragma unroll
  for (int h = 0; h < 4; ++h) sm[h] = wave_sum(sm[h]);
  if (lane == 0) {
#pragma unroll
    for (int h = 0; h < 4; ++h) { sums[n * 4 + h] = sm[h]; mxs[n * 4 + h] = mx[h]; }
  }
}

// Fused: gat1 aggregation (ELU) -> h1 in LDS -> gat2 linear + attn logits.
__global__ __launch_bounds__(256) void k_agg1lin2(
    const int* __restrict__ csr_src, const int* __restrict__ indptr,
    const float* __restrict__ als, const float* __restrict__ ald,
    const float* __restrict__ sums, const float* __restrict__ mxs, size_t ss,
    const unsigned short* __restrict__ hlin, size_t hs, const float* __restrict__ b1,
    const float* __restrict__ W2, const float* __restrict__ as2, const float* __restrict__ ad2,
    unsigned short* __restrict__ hlin2, size_t h2s,
    float* __restrict__ als2, float* __restrict__ ald2, size_t a2s) {
  size_t t = blockIdx.y;
  als += t * ss; ald += t * ss; sums += t * ss; mxs += t * ss; hlin += t * hs;
  hlin2 += t * h2s; als2 += t * a2s; ald2 += t * a2s;
  int n = blockIdx.x;
  int j = threadIdx.x;
  int w = j >> 6, lane = j & 63;
  __shared__ float sh1[C1_];
  __shared__ float part[4][68];
  int s0 = indptr[n], s1 = indptr[n + 1];
  float inv = 1.f / (sums[n * 4 + w] + 1e-16f);
  float mxw = mxs[n * 4 + w];
  float adv = ald[n * 4 + w];
  float acc = 0.f;
  int e = s0;
  for (; e + 4 <= s1; e += 4) {
    int i0 = csr_src[e], i1 = csr_src[e + 1], i2 = csr_src[e + 2], i3 = csr_src[e + 3];
    float s0v = als[i0 * 4 + w] + adv;
    float s1v = als[i1 * 4 + w] + adv;
    float s2v = als[i2 * 4 + w] + adv;
    float s3v = als[i3 * 4 + w] + adv;
    s0v = s0v >= 0.f ? s0v : 0.2f * s0v;
    s1v = s1v >= 0.f ? s1v : 0.2f * s1v;
    s2v = s2v >= 0.f ? s2v : 0.2f * s2v;
    s3v = s3v >= 0.f ? s3v : 0.2f * s3v;
    float a0 = __expf(s0v - mxw) * inv;
    float a1 = __expf(s1v - mxw) * inv;
    float a2 = __expf(s2v - mxw) * inv;
    float a3 = __expf(s3v - mxw) * inv;
    float g0 = h2f(hlin[(size_t)i0 * C1_ + j]);
    float g1 = h2f(hlin[(size_t)i1 * C1_ + j]);
    float g2 = h2f(hlin[(size_t)i2 * C1_ + j]);
    float g3 = h2f(hlin[(size_t)i3 * C1_ + j]);
    acc = fmaf(a0, g0, acc);
    acc = fmaf(a1, g1, acc);
    acc = fmaf(a2, g2, acc);
    acc = fmaf(a3, g3, acc);
  }
  for (; e < s1; ++e) {
    int s = csr_src[e];
    float sc = als[s * 4 + w] + adv;
    sc = sc >= 0.f ? sc : 0.2f * sc;
    acc = fmaf(__expf(sc - mxw) * inv, h2f(hlin[(size_t)s * C1_ + j]), acc);
  }
  float o = acc + b1[j];
  sh1[j] = o > 0.f ? o : expm1f(o);
  __syncthreads();
  float pw = 0.f;
#pragma unroll 4
  for (int kk = 0; kk < 64; ++kk) {
    int k = w * 64 + kk;
    pw = fmaf(sh1[k], W2[k * HID_ + lane], pw);
  }
  part[w][lane] = pw;
  __syncthreads();
  if (w == 0) {
    float a2 = part[0][lane] + part[1][lane] + part[2][lane] + part[3][lane];
    hlin2[(size_t)n * HID_ + lane] = f2h(a2);
    float vs = wave_sum(a2 * as2[lane]);
    float vd = wave_sum(a2 * ad2[lane]);
    if (lane == 0) { als2[n] = vs; ald2[n] = vd; }
  }
}

__global__ __launch_bounds__(256) void k_gat2_attn(
    const int* __restrict__ csr_src, const int* __restrict__ indptr,
    const float* __restrict__ als, const float* __restrict__ ald, size_t a2s,
    float* __restrict__ sums, float* __restrict__ mxs, size_t s2s) {
  size_t t = blockIdx.y;
  als += t * a2s; ald += t * a2s; sums += t * s2s; mxs += t * s2s;
  int w = threadIdx.x >> 6, lane = threadIdx.x & 63;
  int n = blockIdx.x * 4 + w;
  int s0 = indptr[n], s1 = indptr[n + 1];
  float adv = ald[n];
  float mx = -1e30f, sm = 0.f;
  for (int e = s0 + lane; e < s1; e += 64) {
    float sc = als[csr_src[e]] + adv;
    sc = sc >= 0.f ? sc : 0.2f * sc;
    mx = fmaxf(mx, sc);
  }
#pragma unroll
  for (int off = 32; off; off >>= 1) mx = fmaxf(mx, __shfl_xor(mx, off));
  for (int e = s0 + lane; e < s1; e += 64) {
    float sc = als[csr_src[e]] + adv;
    sc = sc >= 0.f ? sc : 0.2f * sc;
    sm += __expf(sc - mx);
  }
  sm = wave_sum(sm);
  if (lane == 0) { sums[n] = sm; mxs[n] = mx; }
}

// writes h2 as fp16 (A-operand of the layer-0 input MFMA); recomputed weights
__global__ __launch_bounds__(256) void k_gat2_agg(
    const int* __restrict__ csr_src, const int* __restrict__ indptr,
    const float* __restrict__ als, const float* __restrict__ ald,
    const float* __restrict__ sums, const float* __restrict__ mxs, size_t s2s,
    const unsigned short* __restrict__ hlin2, size_t h2s, const float* __restrict__ b2,
    unsigned short* __restrict__ h2f16, size_t hos) {
  size_t t = blockIdx.y;
  als += t * s2s; ald += t * s2s; sums += t * s2s; mxs += t * s2s;
  hlin2 += t * h2s; h2f16 += t * hos;
  int w = threadIdx.x >> 6, lane = threadIdx.x & 63;
  int n = blockIdx.x * 4 + w;
  int s0 = indptr[n], s1 = indptr[n + 1];
  float inv = 1.f / (sums[n] + 1e-16f);
  float mxv = mxs[n];
  float adv = ald[n];
  float acc = 0.f;
  int e = s0;
  for (; e + 4 <= s1; e += 4) {
    int i0 = csr_src[e], i1 = csr_src[e + 1], i2 = csr_src[e + 2], i3 = csr_src[e + 3];
    float s0v = als[i0] + adv;
    float s1v = als[i1] + adv;
    float s2v = als[i2] + adv;
    float s3v = als[i3] + adv;
    s0v = s0v >= 0.f ? s0v : 0.2f * s0v;
    s1v = s1v >= 0.f ? s1v : 0.2f * s1v;
    s2v = s2v >= 0.f ? s2v : 0.2f * s2v;
    s3v = s3v >= 0.f ? s3v : 0.2f * s3v;
    float a0 = __expf(s0v - mxv) * inv;
    float a1 = __expf(s1v - mxv) * inv;
    float a2 = __expf(s2v - mxv) * inv;
    float a3 = __expf(s3v - mxv) * inv;
    float g0 = h2f(hlin2[(size_t)i0 * HID_ + lane]);
    float g1 = h2f(hlin2[(size_t)i1 * HID_ + lane]);
    float g2 = h2f(hlin2[(size_t)i2 * HID_ + lane]);
    float g3 = h2f(hlin2[(size_t)i3 * HID_ + lane]);
    acc = fmaf(a0, g0, acc);
    acc = fmaf(a1, g1, acc);
    acc = fmaf(a2, g2, acc);
    acc = fmaf(a3, g3, acc);
  }
  for (; e < s1; ++e) {
    int s = csr_src[e];
    float sc = als[s] + adv;
    sc = sc >= 0.f ? sc : 0.2f * sc;
    acc = fmaf(__expf(sc - mxv) * inv, h2f(hlin2[(size_t)s * HID_ + lane]), acc);
  }
  h2f16[(size_t)n * HID_ + lane] = f2h(acc + b2[lane]);
}

// ---------------- MFMA GRU step (FROZEN: R9 body, R12 barrier placement) ----
// Structural floor (R3/R4/R13 triple-confirmed): 64 VGPR + 64 AGPR = 128
// regs/wave -> 4 waves/SIMD max; any min-waves > 4 spills the accumulators.
__device__ __forceinline__ void mfma1h(f4v& acc, h8v a, h8v b) {
  acc = __builtin_amdgcn_mfma_f32_16x16x32_f16(a, b, acc, 0, 0, 0);
}

__device__ __forceinline__ void mfma_pass(
    const unsigned short* A_,
    const unsigned short* __restrict__ Bh_,
    int w, int lane, f4v Cr[MT_], f4v Cz[MT_], f4v Cn[MT_]) {
  const int mrow = lane & 15, quad = lane >> 4;
#pragma unroll
  for (int ks = 0; ks < 4; ++ks) {
    h8v A[MT_];
    const int aoff = mrow * LDP_ + ks * 32 + quad * 8;
#pragma unroll
    for (int mt = 0; mt < MT_; ++mt) A[mt] = *(const h8v*)(A_ + aoff + mt * (16 * LDP_));
    {
      const int nt = w;
      const h8v bh = *(const h8v*)(Bh_ + ((size_t)(nt * 4 + ks) * 64 + lane) * 8);
#pragma unroll
      for (int mt = 0; mt < MT_; ++mt) mfma1h(Cr[mt], A[mt], bh);
    }
    {
      const int nt = 8 + w;
      const h8v bh = *(const h8v*)(Bh_ + ((size_t)(nt * 4 + ks) * 64 + lane) * 8);
#pragma unroll
      for (int mt = 0; mt < MT_; ++mt) mfma1h(Cz[mt], A[mt], bh);
    }
    {
      const int nt = 16 + w;
      const h8v bh = *(const h8v*)(Bh_ + ((size_t)(nt * 4 + ks) * 64 + lane) * 8);
#pragma unroll
      for (int mt = 0; mt < MT_; ++mt) mfma1h(Cn[mt], A[mt], bh);
    }
  }
}

__device__ __forceinline__ void mfma_pass_x(
    const unsigned short* __restrict__ h2,
    const int esrc[MT_], const int edst[MT_],
    const unsigned short* __restrict__ Bh_,
    int w, int lane, f4v Cr[MT_], f4v Cz[MT_], f4v Cn[MT_]) {
  const int quad = lane >> 4;
#pragma unroll
  for (int ks = 0; ks < 4; ++ks) {
    h8v A[MT_];
    const int choff = (ks & 1) * 32 + quad * 8;
#pragma unroll
    for (int mt = 0; mt < MT_; ++mt) {
      const int node = (ks < 2) ? esrc[mt] : edst[mt];
      A[mt] = *(const h8v*)(h2 + (size_t)node * HID_ + choff);
    }
    {
      const int nt = w;
      const h8v bh = *(const h8v*)(Bh_ + ((size_t)(nt * 4 + ks) * 64 + lane) * 8);
#pragma unroll
      for (int mt = 0; mt < MT_; ++mt) mfma1h(Cr[mt], A[mt], bh);
    }
    {
      const int nt = 8 + w;
      const h8v bh = *(const h8v*)(Bh_ + ((size_t)(nt * 4 + ks) * 64 + lane) * 8);
#pragma unroll
      for (int mt = 0; mt < MT_; ++mt) mfma1h(Cz[mt], A[mt], bh);
    }
    {
      const int nt = 16 + w;
      const h8v bh = *(const h8v*)(Bh_ + ((size_t)(nt * 4 + ks) * 64 + lane) * 8);
#pragma unroll
      for (int mt = 0; mt < MT_; ++mt) mfma1h(Cn[mt], A[mt], bh);
    }
  }
}

__global__ __launch_bounds__(512, 4) void k_gru_step(
    const unsigned short* __restrict__ h2, const int* __restrict__ ei,
    int seg_e0, int first, int last,
    const unsigned short* __restrict__ pWih0, const unsigned short* __restrict__ pWhh0,
    const unsigned short* __restrict__ pWih1, const unsigned short* __restrict__ pWhh1,
    const float* __restrict__ bih0, const float* __restrict__ bhh0,
    const float* __restrict__ bih1, const float* __restrict__ bhh1,
    const float* __restrict__ Wd1, const float* __restrict__ bd1,
    const float* __restrict__ Wd2, const float* __restrict__ bd2,
    unsigned short* __restrict__ h0g, unsigned short* __restrict__ h1g,
    float* __restrict__ out) {
  __shared__ unsigned short h0h[MB_ * LDP_];
  __shared__ unsigned short h1h[MB_ * LDP_];
  const int tid = threadIdx.x;
  const int lane = tid & 63, w = tid >> 6;
  const int col = lane & 15, quad = lane >> 4;
  const int mrow = lane & 15;
  const int le0 = blockIdx.x * MB_;
  const size_t ge0 = (size_t)seg_e0 + le0;

  // edge indices first (pass_x depends on them; earliest issue)
  int esrc[MT_], edst[MT_];
#pragma unroll
  for (int mt = 0; mt < MT_; ++mt) {
    esrc[mt] = ei[ge0 + mt * 16 + mrow];
    edst[mt] = ei[E_ + ge0 + mt * 16 + mrow];
  }
  // stage fp16 states global -> LDS (NT 16B loads)
  if (!first) {
    for (int i = tid; i < MB_ * 16; i += 512) {
      int e = i >> 4, c = (i & 15) * 8;
      *(h8v*)&h0h[e * LDP_ + c] =
          __builtin_nontemporal_load((const h8v*)(h0g + (size_t)(le0 + e) * GH_ + c));
      *(h8v*)&h1h[e * LDP_ + c] =
          __builtin_nontemporal_load((const h8v*)(h1g + (size_t)(le0 + e) * GH_ + c));
    }
  }

  const int cg = w * 16 + col;
  f4v Cr[MT_], Cz[MT_], Cin[MT_], Chn[MT_];

  // ---- layer 0 ----
#pragma unroll
  for (int mt = 0; mt < MT_; ++mt) {
    Cr[mt] = (f4v){0.f, 0.f, 0.f, 0.f};
    Cz[mt] = (f4v){0.f, 0.f, 0.f, 0.f};
    Cin[mt] = (f4v){0.f, 0.f, 0.f, 0.f};
    Chn[mt] = (f4v){0.f, 0.f, 0.f, 0.f};
  }
  mfma_pass_x(h2, esrc, edst, pWih0, w, lane, Cr, Cz, Cin);  // global-only
  __syncthreads();   // staging visible (drain hidden under pass_x)
  if (!first) mfma_pass(h0h, pWhh0, w, lane, Cr, Cz, Chn);
  __syncthreads();   // all reads of old h0h done
  {
    float biR = bih0[cg] + bhh0[cg];
    float biZ = bih0[128 + cg] + bhh0[128 + cg];
    float biNi = bih0[256 + cg], biNh = bhh0[256 + cg];
#pragma unroll
    for (int mt = 0; mt < MT_; ++mt)
#pragma unroll
      for (int reg = 0; reg < 4; ++reg) {
        int e = mt * 16 + quad * 4 + reg;
        float r = sigmoidf_(Cr[mt][reg] + biR);
        float z = sigmoidf_(Cz[mt][reg] + biZ);
        float n = tanhf_(Cin[mt][reg] + biNi + r * (Chn[mt][reg] + biNh));
        float hp = first ? 0.f : h2f(h0h[e * LDP_ + cg]);
        float hv = (1.f - z) * n + z * hp;
        h0h[e * LDP_ + cg] = f2h(hv);
      }
  }
  __syncthreads();   // new h0h visible

  // ---- layer 1 ----
#pragma unroll
  for (int mt = 0; mt < MT_; ++mt) {
    Cr[mt] = (f4v){0.f, 0.f, 0.f, 0.f};
    Cz[mt] = (f4v){0.f, 0.f, 0.f, 0.f};
    Cin[mt] = (f4v){0.f, 0.f, 0.f, 0.f};
    Chn[mt] = (f4v){0.f, 0.f, 0.f, 0.f};
  }
  mfma_pass(h0h, pWih1, w, lane, Cr, Cz, Cin);
  if (!first) mfma_pass(h1h, pWhh1, w, lane, Cr, Cz, Chn);
  __syncthreads();   // old h1h reads done
  {
    float biR = bih1[cg] + bhh1[cg];
    float biZ = bih1[128 + cg] + bhh1[128 + cg];
    float biNi = bih1[256 + cg], biNh = bhh1[256 + cg];
#pragma unroll
    for (int mt = 0; mt < MT_; ++mt)
#pragma unroll
      for (int reg = 0; reg < 4; ++reg) {
        int e = mt * 16 + quad * 4 + reg;
        float r = sigmoidf_(Cr[mt][reg] + biR);
        float z = sigmoidf_(Cz[mt][reg] + biZ);
        float n = tanhf_(Cin[mt][reg] + biNi + r * (Chn[mt][reg] + biNh));
        float hp = first ? 0.f : h2f(h1h[e * LDP_ + cg]);
        float hv = (1.f - z) * n + z * hp;
        if (!last) {
          h1h[e * LDP_ + cg] = f2h(hv);
        } else {
          unsigned short hb = f2h(hv);
          h1h[e * LDP_ + cg] = hb;
          h0h[e * LDP_ + cg] = f2h(hv - h2f(hb));   // lo stash (h0h free)
        }
      }
  }
  __syncthreads();

  if (!last) {
    for (int i = tid; i < MB_ * 16; i += 512) {
      int e = i >> 4, c = (i & 15) * 8;
      __builtin_nontemporal_store(*(const h8v*)&h0h[e * LDP_ + c],
                                  (h8v*)(h0g + (size_t)(le0 + e) * GH_ + c));
      __builtin_nontemporal_store(*(const h8v*)&h1h[e * LDP_ + c],
                                  (h8v*)(h1g + (size_t)(le0 + e) * GH_ + c));
    }
  } else {
    for (int ee = 0; ee < MB_ / 8; ++ee) {
      int e = w * (MB_ / 8) + ee;
      float acc = 0.f;
#pragma unroll
      for (int kc = 0; kc < 16; ++kc) {
        h8v hv8 = *(const h8v*)&h1h[e * LDP_ + kc * 8];
        h8v lv8 = *(const h8v*)&h0h[e * LDP_ + kc * 8];
#pragma unroll
        for (int j = 0; j < 8; ++j) {
          float hvv = (float)hv8[j] + (float)lv8[j];
          acc = fmaf(hvv, Wd1[(kc * 8 + j) * 64 + lane], acc);
        }
      }
      float rv = fmaxf(acc + bd1[lane], 0.f);
      float contrib = wave_sum(rv * Wd2[lane]);
      if (lane == 0) out[ge0 + e] = contrib + bd2[0];
    }
  }
}

// ---------------- launch ----------------
extern "C" void kernel_launch(void* const* d_in, const int* in_sizes, int n_in,
                              void* d_out, int out_size, void* d_ws, size_t ws_size,
                              hipStream_t stream) {
  (void)in_sizes; (void)n_in; (void)out_size;
  const float* x_seq = (const float*)d_in[0];
  const int*   ei    = (const int*)d_in[1];
  const float* W1    = (const float*)d_in[2];
  const float* as1   = (const float*)d_in[3];
  const float* ad1   = (const float*)d_in[4];
  const float* b1    = (const float*)d_in[5];
  const float* W2    = (const float*)d_in[6];
  const float* as2   = (const float*)d_in[7];
  const float* ad2   = (const float*)d_in[8];
  const float* b2    = (const float*)d_in[9];
  const float* Wih0  = (const float*)d_in[10];
  const float* Whh0  = (const float*)d_in[11];
  const float* bih0  = (const float*)d_in[12];
  const float* bhh0  = (const float*)d_in[13];
  const float* Wih1  = (const float*)d_in[14];
  const float* Whh1  = (const float*)d_in[15];
  const float* bih1  = (const float*)d_in[16];
  const float* bhh1  = (const float*)d_in[17];
  const float* Wd1   = (const float*)d_in[18];
  const float* bd1   = (const float*)d_in[19];
  const float* Wd2   = (const float*)d_in[20];
  const float* bd2   = (const float*)d_in[21];
  float* out = (float*)d_out;

  char* p = (char*)d_ws;
  auto alloc = [&](size_t bytes) -> char* {
    char* r = p;
    p += (bytes + 255) & ~(size_t)255;
    return r;
  };
  auto rnd = [](size_t b) { return (b + 255) & ~(size_t)255; };

  // persistent:
  unsigned short* h2_all = (unsigned short*)alloc((size_t)T_ * N_ * HID_ * 2);  // 20.5 MB
  unsigned short* pWih0 = (unsigned short*)alloc(NPACK_ * 2);
  unsigned short* pWhh0 = (unsigned short*)alloc(NPACK_ * 2);
  unsigned short* pWih1 = (unsigned short*)alloc(NPACK_ * 2);
  unsigned short* pWhh1 = (unsigned short*)alloc(NPACK_ * 2);
  int* counts   = (int*)alloc((size_t)N_ * 4);
  int* indptr   = (int*)alloc((size_t)(N_ + 1) * 4);
  int* cursors  = (int*)alloc((size_t)N_ * 4);
  int* csr      = (int*)alloc((size_t)ETOT_ * 4);

  // per-t element strides
  const size_t S_HL1 = (size_t)N_ * C1_;   // hlin1 fp16
  const size_t S_SU1 = (size_t)N_ * 4;     // als1/ald1/sums1/mxs1 fp32
  const size_t S_HL2 = (size_t)N_ * HID_;  // hlin2 fp16
  const size_t S_SC2 = (size_t)N_;         // als2/ald2/sums2/mxs2 fp32

  // Batched mode needs region >= max(GAT T-batched scratch, full-E GRU states).
  size_t gat_batched = rnd(S_HL1 * 2 * T_) + 4 * rnd(S_SU1 * 4 * T_) +
                       rnd(S_HL2 * 2 * T_) + 4 * rnd(S_SC2 * 4 * T_);
  size_t states1 = 2 * rnd((size_t)E_ * GH_ * 2);          // SEG=1 (merged)
  size_t pers_off = (size_t)(p - (char*)d_ws);
  size_t need_b = gat_batched > states1 ? gat_batched : states1;
  const int batched = (ws_size >= pers_off + need_b + (1u << 20)) ? 1 : 0;
  const size_t TB = batched ? T_ : 1;
  const int segs = batched ? 1 : 2;        // merged segments need full-E states
  const int eseg = E_ / segs;

  // REGION: GAT scratch (phase 1) aliased with GRU fp16 states (phase 2).
  char* region = p;
  unsigned short* hlin1 = (unsigned short*)alloc(S_HL1 * 2 * TB);
  float* als1   = (float*)alloc(S_SU1 * 4 * TB);
  float* ald1   = (float*)alloc(S_SU1 * 4 * TB);
  float* sums1  = (float*)alloc(S_SU1 * 4 * TB);
  float* mxs1   = (float*)alloc(S_SU1 * 4 * TB);
  unsigned short* hlin2 = (unsigned short*)alloc(S_HL2 * 2 * TB);
  float* als2   = (float*)alloc(S_SC2 * 4 * TB);
  float* ald2   = (float*)alloc(S_SC2 * 4 * TB);
  float* sums2  = (float*)alloc(S_SC2 * 4 * TB);
  float* mxs2   = (float*)alloc(S_SC2 * 4 * TB);
  // GRU view (same region): fp16 states 2 x (eseg*GH*2) bytes
  unsigned short* h0g = (unsigned short*)(region);
  unsigned short* h1g = (unsigned short*)(region + rnd((size_t)eseg * GH_ * 2));

  (void)hipMemsetAsync(counts, 0, (size_t)N_ * 4, stream);

  k_hist<<<(ETOT_ + 255) / 256, 256, 0, stream>>>(ei, counts);
  k_scan<<<1, 1024, 0, stream>>>(counts, indptr);
  k_copy<<<(N_ + 255) / 256, 256, 0, stream>>>(indptr, cursors);
  k_scatter<<<(ETOT_ + 255) / 256, 256, 0, stream>>>(ei, cursors, csr);
  const int pb = (NPACK_ + 255) / 256;
  k_packW16<<<pb, 256, 0, stream>>>(Wih0, pWih0);
  k_packW16<<<pb, 256, 0, stream>>>(Whh0, pWhh0);
  k_packW16<<<pb, 256, 0, stream>>>(Wih1, pWih1);
  k_packW16<<<pb, 256, 0, stream>>>(Whh1, pWhh1);

  const int TL = batched ? 1 : T_;
  const unsigned gy = batched ? T_ : 1;
  for (int t = 0; t < TL; ++t) {
    const float* xt = batched ? x_seq : x_seq + (size_t)t * N_ * FIN_;
    unsigned short* h2t = batched ? h2_all : h2_all + (size_t)t * N_ * HID_;
    k_gat1_lin<<<dim3(N_, gy), 256, 0, stream>>>(
        xt, (size_t)N_ * FIN_, W1, as1, ad1, hlin1, S_HL1, als1, ald1, S_SU1);
    k_gat1_attn<<<dim3(N_ / 4, gy), 256, 0, stream>>>(
        csr, indptr, als1, ald1, S_SU1, sums1, mxs1, S_SU1);
    k_agg1lin2<<<dim3(N_, gy), 256, 0, stream>>>(
        csr, indptr, als1, ald1, sums1, mxs1, S_SU1, hlin1, S_HL1, b1,
        W2, as2, ad2, hlin2, S_HL2, als2, ald2, S_SC2);
    k_gat2_attn<<<dim3(N_ / 4, gy), 256, 0, stream>>>(
        csr, indptr, als2, ald2, S_SC2, sums2, mxs2, S_SC2);
    k_gat2_agg<<<dim3(N_ / 4, gy), 256, 0, stream>>>(
        csr, indptr, als2, ald2, sums2, mxs2, S_SC2, hlin2, S_HL2, b2, h2t, S_HL2);
  }

  for (int seg = 0; seg < segs; ++seg) {
    for (int t = 0; t < T_; ++t) {
      const unsigned short* h2t = h2_all + (size_t)t * N_ * HID_;
      k_gru_step<<<eseg / MB_, 512, 0, stream>>>(
          h2t, ei, seg * eseg, (t == 0) ? 1 : 0, (t == T_ - 1) ? 1 : 0,
          pWih0, pWhh0, pWih1, pWhh1,
          bih0, bhh0, bih1, bhh1, Wd1, bd1, Wd2, bd2,
          h0g, h1g, out);
    }
  }
}